// Round 1
// baseline (646.230 us; speedup 1.0000x reference)
//
#include <hip/hip_runtime.h>
#include <math.h>

typedef short s16x8 __attribute__((ext_vector_type(8)));
typedef float f32x4 __attribute__((ext_vector_type(4)));
typedef unsigned short u16x4 __attribute__((ext_vector_type(4)));

#define DIM_ 768
#define HID_ 3072
#define NTOK 4096
#define CAP 9216

__device__ __forceinline__ unsigned short f2bf(float f) {
  unsigned u = __float_as_uint(f);
  u += 0x7fffu + ((u >> 16) & 1u);   // RNE
  return (unsigned short)(u >> 16);
}

__device__ __forceinline__ void async_cp16(const void* g, void* l) {
  __builtin_amdgcn_global_load_lds(
      (const __attribute__((address_space(1))) void*)g,
      (__attribute__((address_space(3))) void*)l, 16, 0, 0);
}

// ---------------- 128x128 bf16 MFMA GEMM mainloop -------------------------
// A: bf16 row-major [M][lda]; B: fp32 row-major [N][ldb] (i.e. weight[n][k]).
// C[m][n] = sum_k A[m][k]*B[n][k].  256 threads = 4 waves in 2x2 quadrants.
__device__ __forceinline__ void gemm_tile(
    const unsigned short* __restrict__ A, int lda,
    const float* __restrict__ B, int ldb,
    int K, int row0, int col0,
    unsigned short* lA, unsigned short* lB,
    f32x4 acc[4][4])
{
  const int tid = threadIdx.x;
  const int lane = tid & 63;
  const int w = tid >> 6;
  const int wm = (w >> 1) << 6;
  const int wn = (w & 1) << 6;
  const int g = lane >> 4;
  const int lm = lane & 15;

  for (int k0 = 0; k0 < K; k0 += 32) {
    __syncthreads();
    // stage A: 128x32 bf16 = 8KB via global_load_lds (16B/lane)
#pragma unroll
    for (int it = 0; it < 2; ++it) {
      int c = (w * 2 + it) * 64 + lane;      // chunk 0..511
      int ar = c >> 2, ke = (c & 3) << 3;
      async_cp16(A + (size_t)(row0 + ar) * lda + (k0 + ke),
                 lA + (w * 2 + it) * 512);
    }
    // stage B: 128x32 fp32 -> bf16 convert in regs
#pragma unroll
    for (int it = 0; it < 4; ++it) {
      int f = it * 1024 + tid * 4;
      int br = f >> 5, ke = f & 31;
      const float4 vv = *(const float4*)(B + (size_t)(col0 + br) * ldb + (k0 + ke));
      u16x4 pk;
      pk[0] = f2bf(vv.x); pk[1] = f2bf(vv.y); pk[2] = f2bf(vv.z); pk[3] = f2bf(vv.w);
      *(u16x4*)(lB + br * 32 + ke) = pk;
    }
    __syncthreads();
    s16x8 a_frag[4], b_frag[4];
#pragma unroll
    for (int mt = 0; mt < 4; ++mt)
      a_frag[mt] = *(const s16x8*)(lA + (wm + mt * 16 + lm) * 32 + g * 8);
#pragma unroll
    for (int nt = 0; nt < 4; ++nt)
      b_frag[nt] = *(const s16x8*)(lB + (wn + nt * 16 + lm) * 32 + g * 8);
#pragma unroll
    for (int mt = 0; mt < 4; ++mt)
#pragma unroll
      for (int nt = 0; nt < 4; ++nt)
        acc[mt][nt] = __builtin_amdgcn_mfma_f32_16x16x32_bf16(
            a_frag[mt], b_frag[nt], acc[mt][nt], 0, 0, 0);
  }
}

#define GEMM_PROLOGUE                                   \
  __shared__ unsigned short lA[128 * 32];               \
  __shared__ unsigned short lB[128 * 32];               \
  f32x4 acc[4][4];                                      \
  _Pragma("unroll") for (int a_ = 0; a_ < 4; ++a_)      \
  _Pragma("unroll") for (int b_ = 0; b_ < 4; ++b_) {    \
    acc[a_][b_][0]=0.f; acc[a_][b_][1]=0.f;             \
    acc[a_][b_][2]=0.f; acc[a_][b_][3]=0.f; }           \
  const int lane = threadIdx.x & 63;                    \
  const int w = threadIdx.x >> 6;                       \
  const int wm = (w >> 1) << 6, wn = (w & 1) << 6;      \
  const int g = lane >> 4, lm = lane & 15;

// ---------------- kernels -------------------------------------------------

__global__ __launch_bounds__(256, 2) void k_qkv(
    const unsigned short* __restrict__ hbf, const float* __restrict__ qkvw,
    unsigned short* __restrict__ qkvb)
{
  GEMM_PROLOGUE
  int row0 = blockIdx.x * 128, col0 = blockIdx.y * 128;
  gemm_tile(hbf, DIM_, qkvw, DIM_, DIM_, row0, col0, lA, lB, acc);
#pragma unroll
  for (int mt = 0; mt < 4; ++mt)
#pragma unroll
    for (int nt = 0; nt < 4; ++nt)
#pragma unroll
      for (int i = 0; i < 4; ++i) {
        int m = row0 + wm + mt * 16 + g * 4 + i;
        int n = col0 + wn + nt * 16 + lm;
        int which = (n >= 1536) ? 2 : (n >= 768 ? 1 : 0);
        int d = n - which * 768;
        int head = d >> 6, hd = d & 63;
        int b = m >> 10, nn = m & 1023;
        int bh = b * 12 + head;
        size_t addr = (which < 2)
            ? ((size_t)which * 3145728u + (size_t)bh * 65536u + (size_t)nn * 64 + hd)
            : (6291456u + (size_t)bh * 65536u + (size_t)hd * 1024 + nn);  // V^T
        qkvb[addr] = f2bf(acc[mt][nt][i]);
      }
}

__global__ __launch_bounds__(256, 2) void k_attn(
    const unsigned short* __restrict__ qkv, unsigned short* __restrict__ abuf)
{
  __shared__ unsigned short lK[64 * 64];
  __shared__ unsigned short lV[64 * 64];     // V^T tile: [d][seq]
  __shared__ unsigned short lP[4][16 * 72];  // per-wave P, padded ld=72
  const int tid = threadIdx.x, lane = tid & 63, w = tid >> 6;
  const int g = lane >> 4, lm = lane & 15;
  const int qt = blockIdx.x, bh = blockIdx.y;
  const unsigned short* qsec = qkv + (size_t)bh * 65536u;
  const unsigned short* ksec = qkv + 3145728u + (size_t)bh * 65536u;
  const unsigned short* vsec = qkv + 6291456u + (size_t)bh * 65536u;

  // Q frags (B-operand of S^T): B[k=g*8+j][n=lm] = Q[qrow=lm(+wave base)][k]
  s16x8 bq[2];
  {
    const unsigned short* qp = qsec + (size_t)(qt * 64 + w * 16 + lm) * 64 + g * 8;
    bq[0] = *(const s16x8*)(qp);
    bq[1] = *(const s16x8*)(qp + 32);
  }
  f32x4 oacc[4];
#pragma unroll
  for (int dt = 0; dt < 4; ++dt) { oacc[dt][0]=0.f; oacc[dt][1]=0.f; oacc[dt][2]=0.f; oacc[dt][3]=0.f; }
  float m_i = -3.0e38f, l_i = 0.f;   // state for q-row = lm (replicated x4 groups)

  for (int kt = 0; kt < 16; ++kt) {
#pragma unroll
    for (int it = 0; it < 2; ++it) {
      int c = (w * 2 + it) * 64 + lane;
      // K tile: contiguous 8KB
      async_cp16(ksec + (size_t)kt * 4096 + (size_t)c * 8, lK + (w * 2 + it) * 512);
      // V^T tile: chunk c -> d=c>>3, s8=c&7
      int dd = c >> 3, s8 = c & 7;
      async_cp16(vsec + (size_t)dd * 1024 + kt * 64 + s8 * 8, lV + (w * 2 + it) * 512);
    }
    __syncthreads();
    // S^T = K_tile @ Q^T  (A=K rows, contiguous hd; B=Q rows, contiguous hd)
    f32x4 st[4];
#pragma unroll
    for (int mt = 0; mt < 4; ++mt) {
      f32x4 z; z[0]=0.f; z[1]=0.f; z[2]=0.f; z[3]=0.f;
#pragma unroll
      for (int ks = 0; ks < 2; ++ks) {
        s16x8 a = *(const s16x8*)(lK + (mt * 16 + lm) * 64 + ks * 32 + g * 8);
        z = __builtin_amdgcn_mfma_f32_16x16x32_bf16(a, bq[ks], z, 0, 0, 0);
      }
      st[mt] = z;   // S^T[kcol = mt*16 + g*4 + i][qrow = lm]
    }
    float mx = -3.0e38f;
#pragma unroll
    for (int mt = 0; mt < 4; ++mt) {
      st[mt] *= 0.125f;  // hd^-0.5
#pragma unroll
      for (int i = 0; i < 4; ++i) mx = fmaxf(mx, st[mt][i]);
    }
    mx = fmaxf(mx, __shfl_xor(mx, 16, 64));
    mx = fmaxf(mx, __shfl_xor(mx, 32, 64));
    float mnew = fmaxf(m_i, mx);
    float alpha = expf(m_i - mnew);
    float psum = 0.f;
#pragma unroll
    for (int mt = 0; mt < 4; ++mt) {
      u16x4 pk;
#pragma unroll
      for (int i = 0; i < 4; ++i) {
        float p = expf(st[mt][i] - mnew);
        psum += p;
        pk[i] = f2bf(p);
      }
      // store P (un-transposed) [qrow][kcol]: 4 consecutive kcols -> b64
      *(u16x4*)(&lP[w][lm * 72 + mt * 16 + g * 4]) = pk;
    }
    psum += __shfl_xor(psum, 16, 64);
    psum += __shfl_xor(psum, 32, 64);
    l_i = l_i * alpha + psum;
    m_i = mnew;
    __syncthreads();
    // rescale O by alpha of its own rows (O rows = g*4+i, state lives at lane&15==row)
    float al[4];
#pragma unroll
    for (int i = 0; i < 4; ++i) al[i] = __shfl(alpha, (lane & 48) | (g * 4 + i), 64);
#pragma unroll
    for (int dt = 0; dt < 4; ++dt) {
#pragma unroll
      for (int i = 0; i < 4; ++i) oacc[dt][i] *= al[i];
    }
    // O += P @ V  (A=P rows contiguous k; B=V via V^T rows contiguous k)
#pragma unroll
    for (int ks = 0; ks < 2; ++ks) {
      s16x8 ap = *(const s16x8*)(&lP[w][lm * 72 + ks * 32 + g * 8]);
#pragma unroll
      for (int dt = 0; dt < 4; ++dt) {
        s16x8 bv = *(const s16x8*)(lV + (dt * 16 + lm) * 64 + ks * 32 + g * 8);
        oacc[dt] = __builtin_amdgcn_mfma_f32_16x16x32_bf16(ap, bv, oacc[dt], 0, 0, 0);
      }
    }
    __syncthreads();
  }
  float linv[4];
#pragma unroll
  for (int i = 0; i < 4; ++i)
    linv[i] = 1.f / __shfl(l_i, (lane & 48) | (g * 4 + i), 64);
  int b = bh / 12, head = bh % 12;
#pragma unroll
  for (int dt = 0; dt < 4; ++dt)
#pragma unroll
    for (int i = 0; i < 4; ++i) {
      int q = qt * 64 + w * 16 + g * 4 + i;
      int col = head * 64 + dt * 16 + lm;
      abuf[(size_t)(b * 1024 + q) * DIM_ + col] = f2bf(oacc[dt][i] * linv[i]);
    }
}

__global__ __launch_bounds__(256, 2) void k_proj(
    const unsigned short* __restrict__ abuf, const float* __restrict__ projw,
    const float* __restrict__ projb, const float* __restrict__ x,
    float* __restrict__ x1)
{
  GEMM_PROLOGUE
  int row0 = blockIdx.x * 128, col0 = blockIdx.y * 128;
  gemm_tile(abuf, DIM_, projw, DIM_, DIM_, row0, col0, lA, lB, acc);
#pragma unroll
  for (int mt = 0; mt < 4; ++mt)
#pragma unroll
    for (int nt = 0; nt < 4; ++nt)
#pragma unroll
      for (int i = 0; i < 4; ++i) {
        int m = row0 + wm + mt * 16 + g * 4 + i;
        int n = col0 + wn + nt * 16 + lm;
        size_t idx = (size_t)m * DIM_ + n;
        x1[idx] = acc[mt][nt][i] + projb[n] + x[idx];
      }
}

__global__ __launch_bounds__(256, 2) void k_ffn1(
    const unsigned short* __restrict__ xg, const float* __restrict__ w1,
    const float* __restrict__ b1, const int* __restrict__ off,
    unsigned short* __restrict__ hidden)
{
  int row0 = blockIdx.x * 128, col0 = blockIdx.y * 128;
  if (row0 >= off[8]) return;
  int e = 0;
  while (!(row0 >= off[e] && row0 < off[e + 1])) ++e;
  GEMM_PROLOGUE
  gemm_tile(xg, DIM_, w1 + (size_t)e * HID_ * DIM_, DIM_, DIM_, row0, col0, lA, lB, acc);
#pragma unroll
  for (int mt = 0; mt < 4; ++mt)
#pragma unroll
    for (int nt = 0; nt < 4; ++nt)
#pragma unroll
      for (int i = 0; i < 4; ++i) {
        int m = row0 + wm + mt * 16 + g * 4 + i;
        int n = col0 + wn + nt * 16 + lm;
        float v = acc[mt][nt][i] + b1[e * HID_ + n];
        float ge = 0.5f * v * (1.f + erff(v * 0.70710678118654752f));
        hidden[(size_t)m * HID_ + n] = f2bf(ge);
      }
}

__global__ __launch_bounds__(256, 2) void k_ffn2(
    const unsigned short* __restrict__ hidden, const float* __restrict__ w2,
    const float* __restrict__ b2, const int* __restrict__ off,
    float* __restrict__ ye)
{
  int row0 = blockIdx.x * 128, col0 = blockIdx.y * 128;
  if (row0 >= off[8]) return;
  int e = 0;
  while (!(row0 >= off[e] && row0 < off[e + 1])) ++e;
  GEMM_PROLOGUE
  gemm_tile(hidden, HID_, w2 + (size_t)e * DIM_ * HID_, HID_, HID_, row0, col0, lA, lB, acc);
#pragma unroll
  for (int mt = 0; mt < 4; ++mt)
#pragma unroll
    for (int nt = 0; nt < 4; ++nt)
#pragma unroll
      for (int i = 0; i < 4; ++i) {
        int m = row0 + wm + mt * 16 + g * 4 + i;
        int n = col0 + wn + nt * 16 + lm;
        ye[(size_t)m * DIM_ + n] = acc[mt][nt][i] + b2[e * DIM_ + n];
      }
}

__global__ __launch_bounds__(256) void k_ln1(
    const float* __restrict__ x, const float* __restrict__ gg,
    const float* __restrict__ bb, unsigned short* __restrict__ out)
{
  int t = blockIdx.x, tid = threadIdx.x;
  const float* xr = x + (size_t)t * DIM_;
  float v0 = xr[tid], v1 = xr[tid + 256], v2 = xr[tid + 512];
  float s = v0 + v1 + v2, q = v0 * v0 + v1 * v1 + v2 * v2;
  for (int o = 32; o; o >>= 1) { s += __shfl_xor(s, o, 64); q += __shfl_xor(q, o, 64); }
  __shared__ float red[8];
  int lane = tid & 63, w = tid >> 6;
  if (!lane) { red[w] = s; red[4 + w] = q; }
  __syncthreads();
  s = red[0] + red[1] + red[2] + red[3];
  q = red[4] + red[5] + red[6] + red[7];
  float mean = s * (1.f / 768.f);
  float rstd = rsqrtf(q * (1.f / 768.f) - mean * mean + 1e-5f);
  unsigned short* orow = out + (size_t)t * DIM_;
  orow[tid]       = f2bf((v0 - mean) * rstd * gg[tid]       + bb[tid]);
  orow[tid + 256] = f2bf((v1 - mean) * rstd * gg[tid + 256] + bb[tid + 256]);
  orow[tid + 512] = f2bf((v2 - mean) * rstd * gg[tid + 512] + bb[tid + 512]);
}

__global__ __launch_bounds__(256) void k_ln2gate(
    const float* __restrict__ x1, const float* __restrict__ gg,
    const float* __restrict__ bb, const float* __restrict__ gw,
    const float* __restrict__ gb, unsigned short* __restrict__ h2,
    int* __restrict__ topidx, float* __restrict__ tops)
{
  int t = blockIdx.x, tid = threadIdx.x;
  const float* xr = x1 + (size_t)t * DIM_;
  float v0 = xr[tid], v1 = xr[tid + 256], v2 = xr[tid + 512];
  float s = v0 + v1 + v2, q = v0 * v0 + v1 * v1 + v2 * v2;
  for (int o = 32; o; o >>= 1) { s += __shfl_xor(s, o, 64); q += __shfl_xor(q, o, 64); }
  __shared__ float red[8];
  __shared__ float part[32];
  int lane = tid & 63, w = tid >> 6;
  if (!lane) { red[w] = s; red[4 + w] = q; }
  __syncthreads();
  s = red[0] + red[1] + red[2] + red[3];
  q = red[4] + red[5] + red[6] + red[7];
  float mean = s * (1.f / 768.f);
  float rstd = rsqrtf(q * (1.f / 768.f) - mean * mean + 1e-5f);
  float y0 = (v0 - mean) * rstd * gg[tid]       + bb[tid];
  float y1 = (v1 - mean) * rstd * gg[tid + 256] + bb[tid + 256];
  float y2 = (v2 - mean) * rstd * gg[tid + 512] + bb[tid + 512];
  unsigned short* hrow = h2 + (size_t)t * DIM_;
  hrow[tid] = f2bf(y0); hrow[tid + 256] = f2bf(y1); hrow[tid + 512] = f2bf(y2);
  // fp32 gate logits (avoid bf16-induced expert-selection flips)
#pragma unroll
  for (int e = 0; e < 8; ++e) {
    float p = y0 * gw[e * DIM_ + tid] + y1 * gw[e * DIM_ + tid + 256] + y2 * gw[e * DIM_ + tid + 512];
    for (int o = 32; o; o >>= 1) p += __shfl_xor(p, o, 64);
    if (!lane) part[e * 4 + w] = p;
  }
  __syncthreads();
  if (tid == 0) {
    float lg[8];
#pragma unroll
    for (int e = 0; e < 8; ++e)
      lg[e] = part[e * 4] + part[e * 4 + 1] + part[e * 4 + 2] + part[e * 4 + 3] + gb[e];
    int i0 = 0; float b0 = lg[0];
#pragma unroll
    for (int e = 1; e < 8; ++e) if (lg[e] > b0) { b0 = lg[e]; i0 = e; }
    int i1 = (i0 == 0) ? 1 : 0; float b1v = lg[i1];
#pragma unroll
    for (int e = 0; e < 8; ++e)
      if (e != i0 && lg[e] > b1v) { b1v = lg[e]; i1 = e; }
    float e1 = expf(b1v - b0);
    float s0 = 1.f / (1.f + e1);
    topidx[t * 2] = i0; topidx[t * 2 + 1] = i1;
    tops[t * 2] = s0;  tops[t * 2 + 1] = e1 / (1.f + e1);
  }
}

__global__ void k_count(const int* __restrict__ topidx, int* __restrict__ cnt) {
  int i = blockIdx.x * 256 + threadIdx.x;
  atomicAdd(&cnt[topidx[i]], 1);
}

__global__ void k_offsets(const int* __restrict__ cnt, int* __restrict__ off) {
  if (threadIdx.x == 0) {
    int a = 0;
    for (int e = 0; e < 8; ++e) { off[e] = a; a += (cnt[e] + 127) & ~127; }
    off[8] = a;
  }
}

__global__ void k_scatter(const int* __restrict__ topidx, int* __restrict__ fill,
                          const int* __restrict__ off, int* __restrict__ pos_of) {
  int i = blockIdx.x * 256 + threadIdx.x;
  int e = topidx[i];
  pos_of[i] = off[e] + atomicAdd(&fill[e], 1);
}

__global__ void k_gather(const unsigned short* __restrict__ h2,
                         const int* __restrict__ pos_of,
                         unsigned short* __restrict__ xg) {
  int pair = blockIdx.x, tid = threadIdx.x;   // 192 threads
  int pos = pos_of[pair], t = pair >> 1;
  ((uint2*)xg)[(size_t)pos * 192 + tid] = ((const uint2*)h2)[(size_t)t * 192 + tid];
}

__global__ void k_combine(const float* __restrict__ x1, const float* __restrict__ ye,
                          const int* __restrict__ pos_of, const float* __restrict__ tops,
                          float* __restrict__ out) {
  int t = blockIdx.x, tid = threadIdx.x;
  int p0 = pos_of[t * 2], p1 = pos_of[t * 2 + 1];
  float s0 = tops[t * 2], s1 = tops[t * 2 + 1];
  const float* xr = x1 + (size_t)t * DIM_;
  const float* y0 = ye + (size_t)p0 * DIM_;
  const float* y1 = ye + (size_t)p1 * DIM_;
  float* orow = out + (size_t)t * DIM_;
  orow[tid]       = xr[tid]       + s0 * y0[tid]       + s1 * y1[tid];
  orow[tid + 256] = xr[tid + 256] + s0 * y0[tid + 256] + s1 * y1[tid + 256];
  orow[tid + 512] = xr[tid + 512] + s0 * y0[tid + 512] + s1 * y1[tid + 512];
}

extern "C" void kernel_launch(void* const* d_in, const int* in_sizes, int n_in,
                              void* d_out, int out_size, void* d_ws, size_t ws_size,
                              hipStream_t stream) {
  const float* x     = (const float*)d_in[0];
  const float* ln1g  = (const float*)d_in[1];
  const float* ln1b  = (const float*)d_in[2];
  const float* qkvw  = (const float*)d_in[3];
  const float* projw = (const float*)d_in[4];
  const float* projb = (const float*)d_in[5];
  const float* ln2g  = (const float*)d_in[6];
  const float* ln2b  = (const float*)d_in[7];
  const float* gw    = (const float*)d_in[8];
  const float* gb    = (const float*)d_in[9];
  const float* w1    = (const float*)d_in[10];
  const float* b1    = (const float*)d_in[11];
  const float* w2    = (const float*)d_in[12];
  const float* b2    = (const float*)d_in[13];
  float* out = (float*)d_out;

  char* base = (char*)d_ws;
  unsigned short* hbf    = (unsigned short*)(base + 0);          //  6291456 B (reused as h2)
  unsigned short* qkvb   = (unsigned short*)(base + 6291456);    // 18874368 B (reused as xg)
  unsigned short* abuf   = (unsigned short*)(base + 25165824);   //  6291456 B
  float*          x1     = (float*)(base + 31457280);            // 12582912 B
  unsigned short* hidden = (unsigned short*)(base + 44040192);   // 56623104 B
  float*          ye     = (float*)(base + 100663296);           // 28311552 B
  int*   topidx = (int*)(base + 128974848);
  float* tops   = (float*)(base + 129007616);
  int*   pos_of = (int*)(base + 129040384);
  int*   cnt    = (int*)(base + 129073152);   // cnt[8] + fill[8]
  int*   fill   = cnt + 8;
  int*   off    = (int*)(base + 129073280);
  unsigned short* xg = qkvb;
  unsigned short* h2 = hbf;

  k_ln1<<<NTOK, 256, 0, stream>>>(x, ln1g, ln1b, hbf);
  k_qkv<<<dim3(32, 18), 256, 0, stream>>>(hbf, qkvw, qkvb);
  k_attn<<<dim3(16, 48), 256, 0, stream>>>(qkvb, abuf);
  k_proj<<<dim3(32, 6), 256, 0, stream>>>(abuf, projw, projb, x, x1);
  k_ln2gate<<<NTOK, 256, 0, stream>>>(x1, ln2g, ln2b, gw, gb, h2, topidx, tops);
  hipMemsetAsync(cnt, 0, 64, stream);
  k_count<<<32, 256, 0, stream>>>(topidx, cnt);
  k_offsets<<<1, 64, 0, stream>>>(cnt, off);
  hipMemsetAsync(xg, 0, (size_t)CAP * DIM_ * 2, stream);
  k_scatter<<<32, 256, 0, stream>>>(topidx, fill, off, pos_of);
  k_gather<<<8192, 192, 0, stream>>>(h2, pos_of, xg);
  k_ffn1<<<dim3(72, 24), 256, 0, stream>>>(xg, w1, b1, off, hidden);
  k_ffn2<<<dim3(72, 6), 256, 0, stream>>>(hidden, w2, b2, off, ye);
  k_combine<<<NTOK, 256, 0, stream>>>(x1, ye, pos_of, tops, out);
}

// Round 2
// 548.509 us; speedup vs baseline: 1.1782x; 1.1782x over previous
//
#include <hip/hip_runtime.h>
#include <math.h>

typedef short s16x8 __attribute__((ext_vector_type(8)));
typedef float f32x4 __attribute__((ext_vector_type(4)));
typedef unsigned short u16x4 __attribute__((ext_vector_type(4)));
typedef unsigned short u16x8 __attribute__((ext_vector_type(8)));

#define DIM_ 768
#define HID_ 3072
#define NTOK 4096
#define CAP 9216

__device__ __forceinline__ unsigned short f2bf(float f) {
  unsigned u = __float_as_uint(f);
  u += 0x7fffu + ((u >> 16) & 1u);   // RNE
  return (unsigned short)(u >> 16);
}
__device__ __forceinline__ float bf2f(unsigned short u) {
  return __uint_as_float(((unsigned)u) << 16);
}

__device__ __forceinline__ void async_cp16(const void* g, void* l) {
  __builtin_amdgcn_global_load_lds(
      (const __attribute__((address_space(1))) void*)g,
      (__attribute__((address_space(3))) void*)l, 16, 0, 0);
}

// ---------------- 128x128 bf16 MFMA GEMM mainloop -------------------------
// A: bf16 row-major [M][lda]; B: bf16 (BBF) or fp32 row-major [N][ldb].
// C[m][n] = sum_k A[m][k]*B[n][k].  256 threads = 4 waves in 2x2 quadrants.
// LDS k-slot XOR swizzle (slot ^= (row>>1)&3) kills 8-way bank conflicts on
// the ds_read_b128 frag fetch (row stride 64B aliases 16 lanes to 2 quads).
template<bool BBF>
__device__ __forceinline__ void gemm_tile(
    const unsigned short* __restrict__ A, int lda,
    const void* __restrict__ Bv, int ldb,
    int kbeg, int kend, int row0, int col0,
    unsigned short* lA, unsigned short* lB,
    f32x4 acc[4][4])
{
  const int tid = threadIdx.x;
  const int lane = tid & 63;
  const int w = tid >> 6;
  const int wm = (w >> 1) << 6;
  const int wn = (w & 1) << 6;
  const int g = lane >> 4;
  const int lm = lane & 15;

  for (int k0 = kbeg; k0 < kend; k0 += 32) {
    __syncthreads();
#pragma unroll
    for (int it = 0; it < 2; ++it) {
      int c = (w * 2 + it) * 64 + lane;
      int ar = c >> 2, ks = ((c & 3) ^ ((ar >> 1) & 3)) << 3;
      async_cp16(A + (size_t)(row0 + ar) * lda + (k0 + ks),
                 lA + (w * 2 + it) * 512);
    }
    if constexpr (BBF) {
      const unsigned short* Bb = (const unsigned short*)Bv;
#pragma unroll
      for (int it = 0; it < 2; ++it) {
        int c = (w * 2 + it) * 64 + lane;
        int br = c >> 2, ks = ((c & 3) ^ ((br >> 1) & 3)) << 3;
        async_cp16(Bb + (size_t)(col0 + br) * ldb + (k0 + ks),
                   lB + (w * 2 + it) * 512);
      }
    } else {
      const float* Bf = (const float*)Bv;
#pragma unroll
      for (int it = 0; it < 4; ++it) {
        int f = it * 1024 + tid * 4;
        int br = f >> 5, ke = f & 31;
        const float4 vv = *(const float4*)(Bf + (size_t)(col0 + br) * ldb + (k0 + ke));
        u16x4 pk;
        pk[0] = f2bf(vv.x); pk[1] = f2bf(vv.y); pk[2] = f2bf(vv.z); pk[3] = f2bf(vv.w);
        int ksw = (((ke >> 3) ^ ((br >> 1) & 3)) << 3) + (ke & 7);
        *(u16x4*)(lB + br * 32 + ksw) = pk;
      }
    }
    __syncthreads();
    s16x8 a_frag[4], b_frag[4];
#pragma unroll
    for (int mt = 0; mt < 4; ++mt) {
      int ra = wm + mt * 16 + lm;
      a_frag[mt] = *(const s16x8*)(lA + ra * 32 + ((g ^ ((ra >> 1) & 3)) << 3));
    }
#pragma unroll
    for (int nt = 0; nt < 4; ++nt) {
      int cb = wn + nt * 16 + lm;
      b_frag[nt] = *(const s16x8*)(lB + cb * 32 + ((g ^ ((cb >> 1) & 3)) << 3));
    }
#pragma unroll
    for (int mt = 0; mt < 4; ++mt)
#pragma unroll
      for (int nt = 0; nt < 4; ++nt)
        acc[mt][nt] = __builtin_amdgcn_mfma_f32_16x16x32_bf16(
            a_frag[mt], b_frag[nt], acc[mt][nt], 0, 0, 0);
  }
}

#define GEMM_PROLOGUE                                   \
  __shared__ unsigned short lA[128 * 32];               \
  __shared__ unsigned short lB[128 * 32];               \
  f32x4 acc[4][4];                                      \
  _Pragma("unroll") for (int a_ = 0; a_ < 4; ++a_)      \
  _Pragma("unroll") for (int b_ = 0; b_ < 4; ++b_) {    \
    acc[a_][b_][0]=0.f; acc[a_][b_][1]=0.f;             \
    acc[a_][b_][2]=0.f; acc[a_][b_][3]=0.f; }           \
  const int lane = threadIdx.x & 63;                    \
  const int w = threadIdx.x >> 6;                       \
  const int wm = (w >> 1) << 6, wn = (w & 1) << 6;      \
  const int g = lane >> 4, lm = lane & 15;

// ---------------- kernels -------------------------------------------------

__global__ void k_cvt(const float* __restrict__ s, unsigned short* __restrict__ d, int n) {
  int i = (blockIdx.x * 256 + threadIdx.x) * 8;
  if (i >= n) return;
  float4 a = *(const float4*)(s + i);
  float4 b = *(const float4*)(s + i + 4);
  u16x8 o;
  o[0]=f2bf(a.x); o[1]=f2bf(a.y); o[2]=f2bf(a.z); o[3]=f2bf(a.w);
  o[4]=f2bf(b.x); o[5]=f2bf(b.y); o[6]=f2bf(b.z); o[7]=f2bf(b.w);
  *(u16x8*)(d + i) = o;
}

// grid 576 (1D). XCD-swizzled: per XCD 4 row-tiles, col fastest in groups of 6
// so the A-tile (196KB) is re-read from this XCD's L2 and 6 B-tiles stay resident.
__global__ __launch_bounds__(256, 2) void k_qkv(
    const unsigned short* __restrict__ hbf, const unsigned short* __restrict__ qkvw,
    unsigned short* __restrict__ qkvb)
{
  GEMM_PROLOGUE
  int f = blockIdx.x, xcd = f & 7, s = f >> 3;
  int cg = s / 24, rr = (s % 24) / 6, c = cg * 6 + s % 6;
  int row0 = (xcd * 4 + rr) * 128, col0 = c * 128;
  gemm_tile<true>(hbf, DIM_, qkvw, DIM_, 0, DIM_, row0, col0, lA, lB, acc);
#pragma unroll
  for (int mt = 0; mt < 4; ++mt)
#pragma unroll
    for (int nt = 0; nt < 4; ++nt)
#pragma unroll
      for (int i = 0; i < 4; ++i) {
        int m = row0 + wm + mt * 16 + g * 4 + i;
        int n = col0 + wn + nt * 16 + lm;
        int which = (n >= 1536) ? 2 : (n >= 768 ? 1 : 0);
        int d = n - which * 768;
        int head = d >> 6, hd = d & 63;
        int b = m >> 10, nn = m & 1023;
        int bh = b * 12 + head;
        size_t addr = (which < 2)
            ? ((size_t)which * 3145728u + (size_t)bh * 65536u + (size_t)nn * 64 + hd)
            : (6291456u + (size_t)bh * 65536u + (size_t)hd * 1024 + nn);  // V^T
        qkvb[addr] = f2bf(acc[mt][nt][i]);
      }
}

// grid 768 (1D). XCD-swizzled: per XCD 6 bh, K/V (256KB/bh) stay in that L2.
// lK/lV rows are 128B -> 8 slots of 16B, XOR-swizzled by (row&7): un-swizzled,
// all 16 lanes of a frag read hit ONE bank quad (16-way conflict, 5.7x).
__global__ __launch_bounds__(256, 2) void k_attn(
    const unsigned short* __restrict__ qkv, unsigned short* __restrict__ abuf)
{
  __shared__ unsigned short lK[64 * 64];
  __shared__ unsigned short lV[64 * 64];     // V^T tile: [d][seq]
  __shared__ unsigned short lP[4][16 * 72];  // per-wave P, padded ld=72
  const int tid = threadIdx.x, lane = tid & 63, w = tid >> 6;
  const int g = lane >> 4, lm = lane & 15;
  const int f = blockIdx.x, xcd = f & 7, s = f >> 3;
  const int bh = xcd * 6 + (s >> 4);
  const int qt = s & 15;
  const unsigned short* qsec = qkv + (size_t)bh * 65536u;
  const unsigned short* ksec = qkv + 3145728u + (size_t)bh * 65536u;
  const unsigned short* vsec = qkv + 6291456u + (size_t)bh * 65536u;

  s16x8 bq[2];
  {
    const unsigned short* qp = qsec + (size_t)(qt * 64 + w * 16 + lm) * 64 + g * 8;
    bq[0] = *(const s16x8*)(qp);
    bq[1] = *(const s16x8*)(qp + 32);
  }
  f32x4 oacc[4];
#pragma unroll
  for (int dt = 0; dt < 4; ++dt) { oacc[dt][0]=0.f; oacc[dt][1]=0.f; oacc[dt][2]=0.f; oacc[dt][3]=0.f; }
  float m_i = -3.0e38f, l_i = 0.f;

  for (int kt = 0; kt < 16; ++kt) {
#pragma unroll
    for (int it = 0; it < 2; ++it) {
      int c = (w * 2 + it) * 64 + lane;
      int r = c >> 3, sl = (c & 7) ^ (r & 7);
      async_cp16(ksec + (size_t)(kt * 64 + r) * 64 + sl * 8, lK + (w * 2 + it) * 512);
      async_cp16(vsec + (size_t)r * 1024 + kt * 64 + sl * 8, lV + (w * 2 + it) * 512);
    }
    __syncthreads();
    f32x4 st[4];
#pragma unroll
    for (int mt = 0; mt < 4; ++mt) {
      f32x4 z; z[0]=0.f; z[1]=0.f; z[2]=0.f; z[3]=0.f;
#pragma unroll
      for (int ks = 0; ks < 2; ++ks) {
        int ra = mt * 16 + lm;
        s16x8 a = *(const s16x8*)(lK + ra * 64 + (((ks * 4 + g) ^ (ra & 7)) << 3));
        z = __builtin_amdgcn_mfma_f32_16x16x32_bf16(a, bq[ks], z, 0, 0, 0);
      }
      st[mt] = z;   // S^T[kcol = mt*16 + g*4 + i][qrow = lm]
    }
    float mx = -3.0e38f;
#pragma unroll
    for (int mt = 0; mt < 4; ++mt) {
      st[mt] *= 0.125f;
#pragma unroll
      for (int i = 0; i < 4; ++i) mx = fmaxf(mx, st[mt][i]);
    }
    mx = fmaxf(mx, __shfl_xor(mx, 16, 64));
    mx = fmaxf(mx, __shfl_xor(mx, 32, 64));
    float mnew = fmaxf(m_i, mx);
    float alpha = expf(m_i - mnew);
    float psum = 0.f;
#pragma unroll
    for (int mt = 0; mt < 4; ++mt) {
      u16x4 pk;
#pragma unroll
      for (int i = 0; i < 4; ++i) {
        float p = expf(st[mt][i] - mnew);
        psum += p;
        pk[i] = f2bf(p);
      }
      *(u16x4*)(&lP[w][lm * 72 + mt * 16 + g * 4]) = pk;
    }
    psum += __shfl_xor(psum, 16, 64);
    psum += __shfl_xor(psum, 32, 64);
    l_i = l_i * alpha + psum;
    m_i = mnew;
    __syncthreads();
    float al[4];
#pragma unroll
    for (int i = 0; i < 4; ++i) al[i] = __shfl(alpha, (lane & 48) | (g * 4 + i), 64);
#pragma unroll
    for (int dt = 0; dt < 4; ++dt) {
#pragma unroll
      for (int i = 0; i < 4; ++i) oacc[dt][i] *= al[i];
    }
#pragma unroll
    for (int ks = 0; ks < 2; ++ks) {
      s16x8 ap = *(const s16x8*)(&lP[w][lm * 72 + ks * 32 + g * 8]);
#pragma unroll
      for (int dt = 0; dt < 4; ++dt) {
        int rv = dt * 16 + lm;
        s16x8 bv = *(const s16x8*)(lV + rv * 64 + (((ks * 4 + g) ^ (rv & 7)) << 3));
        oacc[dt] = __builtin_amdgcn_mfma_f32_16x16x32_bf16(ap, bv, oacc[dt], 0, 0, 0);
      }
    }
    __syncthreads();
  }
  float linv[4];
#pragma unroll
  for (int i = 0; i < 4; ++i)
    linv[i] = 1.f / __shfl(l_i, (lane & 48) | (g * 4 + i), 64);
  int b = bh / 12, head = bh % 12;
#pragma unroll
  for (int dt = 0; dt < 4; ++dt)
#pragma unroll
    for (int i = 0; i < 4; ++i) {
      int q = qt * 64 + w * 16 + g * 4 + i;
      int col = head * 64 + dt * 16 + lm;
      abuf[(size_t)(b * 1024 + q) * DIM_ + col] = f2bf(oacc[dt][i] * linv[i]);
    }
}

__global__ __launch_bounds__(256, 2) void k_proj(
    const unsigned short* __restrict__ abuf, const unsigned short* __restrict__ projw,
    const float* __restrict__ projb, const float* __restrict__ x,
    float* __restrict__ x1)
{
  GEMM_PROLOGUE
  int row0 = blockIdx.x * 128, col0 = blockIdx.y * 128;
  gemm_tile<true>(abuf, DIM_, projw, DIM_, 0, DIM_, row0, col0, lA, lB, acc);
#pragma unroll
  for (int mt = 0; mt < 4; ++mt)
#pragma unroll
    for (int nt = 0; nt < 4; ++nt)
#pragma unroll
      for (int i = 0; i < 4; ++i) {
        int m = row0 + wm + mt * 16 + g * 4 + i;
        int n = col0 + wn + nt * 16 + lm;
        size_t idx = (size_t)m * DIM_ + n;
        x1[idx] = acc[mt][nt][i] + projb[n] + x[idx];
      }
}

// grid 1728 (1D). Per XCD 9 row-tiles, cols fastest in groups of 8 (A-tile L2 reuse).
template<bool BBF>
__global__ __launch_bounds__(256, 2) void k_ffn1(
    const unsigned short* __restrict__ xg, const void* __restrict__ w1,
    const float* __restrict__ b1, const int* __restrict__ off,
    unsigned short* __restrict__ hidden)
{
  int f = blockIdx.x, xcd = f & 7, s = f >> 3;
  int cg = s / 72, rr = (s % 72) >> 3, c = cg * 8 + (s & 7);
  int row0 = (xcd * 9 + rr) * 128, col0 = c * 128;
  if (row0 >= off[8]) return;
  int e = 0;
  while (!(row0 >= off[e] && row0 < off[e + 1])) ++e;
  GEMM_PROLOGUE
  const char* Bp = (const char*)w1 + (size_t)e * HID_ * DIM_ * (BBF ? 2 : 4);
  gemm_tile<BBF>(xg, DIM_, Bp, DIM_, 0, DIM_, row0, col0, lA, lB, acc);
#pragma unroll
  for (int mt = 0; mt < 4; ++mt)
#pragma unroll
    for (int nt = 0; nt < 4; ++nt)
#pragma unroll
      for (int i = 0; i < 4; ++i) {
        int m = row0 + wm + mt * 16 + g * 4 + i;
        int n = col0 + wn + nt * 16 + lm;
        float v = acc[mt][nt][i] + b1[e * HID_ + n];
        float ge = 0.5f * v * (1.f + erff(v * 0.70710678118654752f));
        hidden[(size_t)m * HID_ + n] = f2bf(ge);
      }
}

// grid 864 (1D): 72 row x 6 col x 2 K-halves (split-K doubles occupancy).
// Per XCD 9 row-tiles; cols+khalf fastest (6 B half-tiles resident, A-chunk
// read 3x back-to-back). Partials in bf16, summed by k_combine.
template<bool BBF>
__global__ __launch_bounds__(256, 2) void k_ffn2(
    const unsigned short* __restrict__ hidden, const void* __restrict__ w2,
    const float* __restrict__ b2, const int* __restrict__ off,
    unsigned short* __restrict__ ye0, unsigned short* __restrict__ ye1)
{
  int f = blockIdx.x, xcd = f & 7, s = f >> 3;
  int cg = s / 54, rem = s % 54;
  int rr = rem / 6, kk = (rem % 6) / 3, c = cg * 3 + rem % 3;
  int row0 = (xcd * 9 + rr) * 128, col0 = c * 128;
  if (row0 >= off[8]) return;
  int e = 0;
  while (!(row0 >= off[e] && row0 < off[e + 1])) ++e;
  GEMM_PROLOGUE
  const char* Bp = (const char*)w2 + (size_t)e * DIM_ * HID_ * (BBF ? 2 : 4);
  gemm_tile<BBF>(hidden, HID_, Bp, HID_, kk * 1536, kk * 1536 + 1536, row0, col0, lA, lB, acc);
  unsigned short* yh = kk ? ye1 : ye0;
#pragma unroll
  for (int mt = 0; mt < 4; ++mt)
#pragma unroll
    for (int nt = 0; nt < 4; ++nt)
#pragma unroll
      for (int i = 0; i < 4; ++i) {
        int m = row0 + wm + mt * 16 + g * 4 + i;
        int n = col0 + wn + nt * 16 + lm;
        float v = acc[mt][nt][i] + (kk ? 0.f : b2[e * DIM_ + n]);
        yh[(size_t)m * DIM_ + n] = f2bf(v);
      }
}

__global__ __launch_bounds__(256) void k_ln1(
    const float* __restrict__ x, const float* __restrict__ gg,
    const float* __restrict__ bb, unsigned short* __restrict__ out)
{
  int t = blockIdx.x, tid = threadIdx.x;
  const float* xr = x + (size_t)t * DIM_;
  float v0 = xr[tid], v1 = xr[tid + 256], v2 = xr[tid + 512];
  float s = v0 + v1 + v2, q = v0 * v0 + v1 * v1 + v2 * v2;
  for (int o = 32; o; o >>= 1) { s += __shfl_xor(s, o, 64); q += __shfl_xor(q, o, 64); }
  __shared__ float red[8];
  int lane = tid & 63, w = tid >> 6;
  if (!lane) { red[w] = s; red[4 + w] = q; }
  __syncthreads();
  s = red[0] + red[1] + red[2] + red[3];
  q = red[4] + red[5] + red[6] + red[7];
  float mean = s * (1.f / 768.f);
  float rstd = rsqrtf(q * (1.f / 768.f) - mean * mean + 1e-5f);
  unsigned short* orow = out + (size_t)t * DIM_;
  orow[tid]       = f2bf((v0 - mean) * rstd * gg[tid]       + bb[tid]);
  orow[tid + 256] = f2bf((v1 - mean) * rstd * gg[tid + 256] + bb[tid + 256]);
  orow[tid + 512] = f2bf((v2 - mean) * rstd * gg[tid + 512] + bb[tid + 512]);
}

__global__ __launch_bounds__(256) void k_ln2gate(
    const float* __restrict__ x1, const float* __restrict__ gg,
    const float* __restrict__ bb, const float* __restrict__ gw,
    const float* __restrict__ gb, unsigned short* __restrict__ h2,
    int* __restrict__ topidx, float* __restrict__ tops)
{
  int t = blockIdx.x, tid = threadIdx.x;
  const float* xr = x1 + (size_t)t * DIM_;
  float v0 = xr[tid], v1 = xr[tid + 256], v2 = xr[tid + 512];
  float s = v0 + v1 + v2, q = v0 * v0 + v1 * v1 + v2 * v2;
  for (int o = 32; o; o >>= 1) { s += __shfl_xor(s, o, 64); q += __shfl_xor(q, o, 64); }
  __shared__ float red[8];
  __shared__ float part[32];
  int lane = tid & 63, w = tid >> 6;
  if (!lane) { red[w] = s; red[4 + w] = q; }
  __syncthreads();
  s = red[0] + red[1] + red[2] + red[3];
  q = red[4] + red[5] + red[6] + red[7];
  float mean = s * (1.f / 768.f);
  float rstd = rsqrtf(q * (1.f / 768.f) - mean * mean + 1e-5f);
  float y0 = (v0 - mean) * rstd * gg[tid]       + bb[tid];
  float y1 = (v1 - mean) * rstd * gg[tid + 256] + bb[tid + 256];
  float y2 = (v2 - mean) * rstd * gg[tid + 512] + bb[tid + 512];
  unsigned short* hrow = h2 + (size_t)t * DIM_;
  hrow[tid] = f2bf(y0); hrow[tid + 256] = f2bf(y1); hrow[tid + 512] = f2bf(y2);
#pragma unroll
  for (int e = 0; e < 8; ++e) {
    float p = y0 * gw[e * DIM_ + tid] + y1 * gw[e * DIM_ + tid + 256] + y2 * gw[e * DIM_ + tid + 512];
    for (int o = 32; o; o >>= 1) p += __shfl_xor(p, o, 64);
    if (!lane) part[e * 4 + w] = p;
  }
  __syncthreads();
  if (tid == 0) {
    float lg[8];
#pragma unroll
    for (int e = 0; e < 8; ++e)
      lg[e] = part[e * 4] + part[e * 4 + 1] + part[e * 4 + 2] + part[e * 4 + 3] + gb[e];
    int i0 = 0; float b0 = lg[0];
#pragma unroll
    for (int e = 1; e < 8; ++e) if (lg[e] > b0) { b0 = lg[e]; i0 = e; }
    int i1 = (i0 == 0) ? 1 : 0; float b1v = lg[i1];
#pragma unroll
    for (int e = 0; e < 8; ++e)
      if (e != i0 && lg[e] > b1v) { b1v = lg[e]; i1 = e; }
    float e1 = expf(b1v - b0);
    float s0 = 1.f / (1.f + e1);
    topidx[t * 2] = i0; topidx[t * 2 + 1] = i1;
    tops[t * 2] = s0;  tops[t * 2 + 1] = e1 / (1.f + e1);
  }
}

__global__ void k_count(const int* __restrict__ topidx, int* __restrict__ cnt) {
  int i = blockIdx.x * 256 + threadIdx.x;
  atomicAdd(&cnt[topidx[i]], 1);
}

__global__ void k_offsets(const int* __restrict__ cnt, int* __restrict__ off) {
  if (threadIdx.x == 0) {
    int a = 0;
    for (int e = 0; e < 8; ++e) { off[e] = a; a += (cnt[e] + 127) & ~127; }
    off[8] = a;
  }
}

__global__ void k_scatter(const int* __restrict__ topidx, int* __restrict__ fill,
                          const int* __restrict__ off, int* __restrict__ pos_of) {
  int i = blockIdx.x * 256 + threadIdx.x;
  int e = topidx[i];
  pos_of[i] = off[e] + atomicAdd(&fill[e], 1);
}

__global__ void k_gather(const unsigned short* __restrict__ h2,
                         const int* __restrict__ pos_of,
                         unsigned short* __restrict__ xg) {
  int pair = blockIdx.x, tid = threadIdx.x;   // 192 threads
  int pos = pos_of[pair], t = pair >> 1;
  ((uint2*)xg)[(size_t)pos * 192 + tid] = ((const uint2*)h2)[(size_t)t * 192 + tid];
}

__global__ void k_combine(const float* __restrict__ x1,
                          const unsigned short* __restrict__ y0h,
                          const unsigned short* __restrict__ y1h,
                          const int* __restrict__ pos_of, const float* __restrict__ tops,
                          float* __restrict__ out) {
  int t = blockIdx.x, tid = threadIdx.x;
  int p0 = pos_of[t * 2], p1 = pos_of[t * 2 + 1];
  float s0 = tops[t * 2], s1 = tops[t * 2 + 1];
  const float* xr = x1 + (size_t)t * DIM_;
  const unsigned short* a0 = y0h + (size_t)p0 * DIM_;
  const unsigned short* a1 = y1h + (size_t)p0 * DIM_;
  const unsigned short* b0 = y0h + (size_t)p1 * DIM_;
  const unsigned short* b1 = y1h + (size_t)p1 * DIM_;
  float* orow = out + (size_t)t * DIM_;
#pragma unroll
  for (int j = 0; j < 3; ++j) {
    int col = tid + j * 256;
    float ya = bf2f(a0[col]) + bf2f(a1[col]);
    float yb = bf2f(b0[col]) + bf2f(b1[col]);
    orow[col] = xr[col] + s0 * ya + s1 * yb;
  }
}

extern "C" void kernel_launch(void* const* d_in, const int* in_sizes, int n_in,
                              void* d_out, int out_size, void* d_ws, size_t ws_size,
                              hipStream_t stream) {
  const float* x     = (const float*)d_in[0];
  const float* ln1g  = (const float*)d_in[1];
  const float* ln1b  = (const float*)d_in[2];
  const float* qkvw  = (const float*)d_in[3];
  const float* projw = (const float*)d_in[4];
  const float* projb = (const float*)d_in[5];
  const float* ln2g  = (const float*)d_in[6];
  const float* ln2b  = (const float*)d_in[7];
  const float* gw    = (const float*)d_in[8];
  const float* gb    = (const float*)d_in[9];
  const float* w1    = (const float*)d_in[10];
  const float* b1    = (const float*)d_in[11];
  const float* w2    = (const float*)d_in[12];
  const float* b2    = (const float*)d_in[13];
  float* out = (float*)d_out;

  char* base = (char*)d_ws;
  unsigned short* hbf    = (unsigned short*)(base + 0);          // 6.29MB (reused as h2)
  unsigned short* qkvb   = (unsigned short*)(base + 6291456);    // 18.9MB (reused as xg)
  unsigned short* abuf   = (unsigned short*)(base + 25165824);   // 6.29MB
  float*          x1     = (float*)(base + 31457280);            // 12.6MB
  unsigned short* hidden = (unsigned short*)(base + 44040192);   // 56.6MB
  unsigned short* ye0    = (unsigned short*)(base + 100663296);  // 14.2MB bf16
  unsigned short* ye1    = (unsigned short*)(base + 114819072);  // 14.2MB bf16

  const size_t FULL_NEED = 209289320;   // + bf16 weight copies
  const bool full = ws_size >= FULL_NEED;
  unsigned short *wqkvbf, *wprojbf, *w1bf = nullptr, *w2bf = nullptr;
  char* small;
  if (full) {
    wqkvbf  = (unsigned short*)(base + 128974848);
    wprojbf = (unsigned short*)(base + 132513792);
    w1bf    = (unsigned short*)(base + 133693440);
    w2bf    = (unsigned short*)(base + 171442176);
    small   = base + 209190912;
  } else {
    // qkv/proj bf16 weights live in the (not-yet-used) hidden region
    wqkvbf  = (unsigned short*)(base + 44040192);
    wprojbf = (unsigned short*)(base + 44040192 + 3538944);
    small   = base + 128974848;
  }
  int*   topidx = (int*)small;
  float* tops   = (float*)(small + 32768);
  int*   pos_of = (int*)(small + 65536);
  int*   cnt    = (int*)(small + 98304);
  int*   fill   = cnt + 8;
  int*   off    = (int*)(small + 98304 + 64);
  unsigned short* xg = qkvb;
  unsigned short* h2 = hbf;

  k_cvt<<<864, 256, 0, stream>>>(qkvw, wqkvbf, 3 * DIM_ * DIM_);
  k_cvt<<<288, 256, 0, stream>>>(projw, wprojbf, DIM_ * DIM_);
  if (full) {
    k_cvt<<<9216, 256, 0, stream>>>(w1, w1bf, 8 * HID_ * DIM_);
    k_cvt<<<9216, 256, 0, stream>>>(w2, w2bf, 8 * HID_ * DIM_);
  }
  k_ln1<<<NTOK, 256, 0, stream>>>(x, ln1g, ln1b, hbf);
  k_qkv<<<576, 256, 0, stream>>>(hbf, wqkvbf, qkvb);
  k_attn<<<768, 256, 0, stream>>>(qkvb, abuf);
  k_proj<<<dim3(32, 6), 256, 0, stream>>>(abuf, wprojbf, projb, x, x1);
  k_ln2gate<<<NTOK, 256, 0, stream>>>(x1, ln2g, ln2b, gw, gb, h2, topidx, tops);
  hipMemsetAsync(cnt, 0, 64, stream);
  k_count<<<32, 256, 0, stream>>>(topidx, cnt);
  k_offsets<<<1, 64, 0, stream>>>(cnt, off);
  hipMemsetAsync(xg, 0, (size_t)CAP * DIM_ * 2, stream);
  k_scatter<<<32, 256, 0, stream>>>(topidx, fill, off, pos_of);
  k_gather<<<8192, 192, 0, stream>>>(h2, pos_of, xg);
  if (full) {
    k_ffn1<true><<<1728, 256, 0, stream>>>(xg, w1bf, b1, off, hidden);
    k_ffn2<true><<<864, 256, 0, stream>>>(hidden, w2bf, b2, off, ye0, ye1);
  } else {
    k_ffn1<false><<<1728, 256, 0, stream>>>(xg, w1, b1, off, hidden);
    k_ffn2<false><<<864, 256, 0, stream>>>(hidden, w2, b2, off, ye0, ye1);
  }
  k_combine<<<NTOK, 256, 0, stream>>>(x1, ye0, ye1, pos_of, tops, out);
}

// Round 3
// 488.445 us; speedup vs baseline: 1.3230x; 1.1230x over previous
//
#include <hip/hip_runtime.h>
#include <math.h>

typedef short s16x8 __attribute__((ext_vector_type(8)));
typedef float f32x4 __attribute__((ext_vector_type(4)));
typedef unsigned short u16x4 __attribute__((ext_vector_type(4)));
typedef unsigned short u16x8 __attribute__((ext_vector_type(8)));

#define DIM_ 768
#define HID_ 3072
#define NTOK 4096
#define CAP 9216

__device__ __forceinline__ unsigned short f2bf(float f) {
  unsigned u = __float_as_uint(f);
  u += 0x7fffu + ((u >> 16) & 1u);   // RNE
  return (unsigned short)(u >> 16);
}
__device__ __forceinline__ float bf2f(unsigned short u) {
  return __uint_as_float(((unsigned)u) << 16);
}

__device__ __forceinline__ void async_cp16(const void* g, void* l) {
  __builtin_amdgcn_global_load_lds(
      (const __attribute__((address_space(1))) void*)g,
      (__attribute__((address_space(3))) void*)l, 16, 0, 0);
}

// ---------------- 128x128 bf16 MFMA GEMM mainloop (double-buffered) -------
// A: bf16 row-major [M][lda]; B: bf16 (BBF) or fp32 row-major [N][ldb].
// C[m][n] = sum_k A[m][k]*B[n][k].  256 threads = 4 waves in 2x2 quadrants.
// Double-buffer: next tile's global_load_lds issues right after the barrier,
// so the vmcnt(0)+s_barrier drain at iteration end overlaps the MFMA phase.
// LDS k-slot XOR swizzle kills the 8-way frag-read bank conflicts.
template<bool BBF>
__device__ __forceinline__ void gemm_loop(
    const unsigned short* __restrict__ A, int lda,
    const void* __restrict__ Bv, int ldb,
    int kbeg, int kend, int row0, int col0,
    unsigned short* lA, unsigned short* lB,   // each 2*4096 elements
    f32x4 acc[4][4])
{
  const int tid = threadIdx.x;
  const int lane = tid & 63;
  const int w = tid >> 6;
  const int wm = (w >> 1) << 6;
  const int wn = (w & 1) << 6;
  const int g = lane >> 4;
  const int lm = lane & 15;

  if constexpr (BBF) {
    const unsigned short* Bb = (const unsigned short*)Bv;
    auto stage = [&](int k0, int p) {
#pragma unroll
      for (int it = 0; it < 2; ++it) {
        int c = (w * 2 + it) * 64 + lane;
        int r = c >> 2, ks = ((c & 3) ^ ((r >> 1) & 3)) << 3;
        async_cp16(A + (size_t)(row0 + r) * lda + (k0 + ks),
                   lA + p * 4096 + (w * 2 + it) * 512);
        async_cp16(Bb + (size_t)(col0 + r) * ldb + (k0 + ks),
                   lB + p * 4096 + (w * 2 + it) * 512);
      }
    };
    stage(kbeg, 0);
    int p = 0;
    for (int k0 = kbeg; k0 < kend; k0 += 32) {
      __syncthreads();                       // buf p staged (drain overlapped prev MFMA)
      if (k0 + 32 < kend) stage(k0 + 32, p ^ 1);
      const unsigned short* bA = lA + p * 4096;
      const unsigned short* bB = lB + p * 4096;
      s16x8 a_frag[4], b_frag[4];
#pragma unroll
      for (int mt = 0; mt < 4; ++mt) {
        int ra = wm + mt * 16 + lm;
        a_frag[mt] = *(const s16x8*)(bA + ra * 32 + ((g ^ ((ra >> 1) & 3)) << 3));
      }
#pragma unroll
      for (int nt = 0; nt < 4; ++nt) {
        int cb = wn + nt * 16 + lm;
        b_frag[nt] = *(const s16x8*)(bB + cb * 32 + ((g ^ ((cb >> 1) & 3)) << 3));
      }
#pragma unroll
      for (int mt = 0; mt < 4; ++mt)
#pragma unroll
        for (int nt = 0; nt < 4; ++nt)
          acc[mt][nt] = __builtin_amdgcn_mfma_f32_16x16x32_bf16(
              a_frag[mt], b_frag[nt], acc[mt][nt], 0, 0, 0);
      p ^= 1;
    }
  } else {
    // fp32-B fallback: single-buffer 2-barrier loop (safety path only)
    const float* Bf = (const float*)Bv;
    for (int k0 = kbeg; k0 < kend; k0 += 32) {
      __syncthreads();
#pragma unroll
      for (int it = 0; it < 2; ++it) {
        int c = (w * 2 + it) * 64 + lane;
        int r = c >> 2, ks = ((c & 3) ^ ((r >> 1) & 3)) << 3;
        async_cp16(A + (size_t)(row0 + r) * lda + (k0 + ks),
                   lA + (w * 2 + it) * 512);
      }
#pragma unroll
      for (int it = 0; it < 4; ++it) {
        int f = it * 1024 + tid * 4;
        int br = f >> 5, ke = f & 31;
        const float4 vv = *(const float4*)(Bf + (size_t)(col0 + br) * ldb + (k0 + ke));
        u16x4 pk;
        pk[0] = f2bf(vv.x); pk[1] = f2bf(vv.y); pk[2] = f2bf(vv.z); pk[3] = f2bf(vv.w);
        int ksw = (((ke >> 3) ^ ((br >> 1) & 3)) << 3) + (ke & 7);
        *(u16x4*)(lB + br * 32 + ksw) = pk;
      }
      __syncthreads();
      s16x8 a_frag[4], b_frag[4];
#pragma unroll
      for (int mt = 0; mt < 4; ++mt) {
        int ra = wm + mt * 16 + lm;
        a_frag[mt] = *(const s16x8*)(lA + ra * 32 + ((g ^ ((ra >> 1) & 3)) << 3));
      }
#pragma unroll
      for (int nt = 0; nt < 4; ++nt) {
        int cb = wn + nt * 16 + lm;
        b_frag[nt] = *(const s16x8*)(lB + cb * 32 + ((g ^ ((cb >> 1) & 3)) << 3));
      }
#pragma unroll
      for (int mt = 0; mt < 4; ++mt)
#pragma unroll
        for (int nt = 0; nt < 4; ++nt)
          acc[mt][nt] = __builtin_amdgcn_mfma_f32_16x16x32_bf16(
              a_frag[mt], b_frag[nt], acc[mt][nt], 0, 0, 0);
    }
  }
}

#define GEMM_PROLOGUE                                   \
  __shared__ unsigned short lA[8192];                   \
  __shared__ unsigned short lB[8192];                   \
  f32x4 acc[4][4];                                      \
  _Pragma("unroll") for (int a_ = 0; a_ < 4; ++a_)      \
  _Pragma("unroll") for (int b_ = 0; b_ < 4; ++b_) {    \
    acc[a_][b_][0]=0.f; acc[a_][b_][1]=0.f;             \
    acc[a_][b_][2]=0.f; acc[a_][b_][3]=0.f; }           \
  const int lane = threadIdx.x & 63;                    \
  const int w = threadIdx.x >> 6;                       \
  const int wm = (w >> 1) << 6, wn = (w & 1) << 6;      \
  const int g = lane >> 4, lm = lane & 15;

// ---------------- kernels -------------------------------------------------

__global__ void k_cvt(const float* __restrict__ s, unsigned short* __restrict__ d, int n) {
  int i = (blockIdx.x * 256 + threadIdx.x) * 8;
  if (i >= n) return;
  float4 a = *(const float4*)(s + i);
  float4 b = *(const float4*)(s + i + 4);
  u16x8 o;
  o[0]=f2bf(a.x); o[1]=f2bf(a.y); o[2]=f2bf(a.z); o[3]=f2bf(a.w);
  o[4]=f2bf(b.x); o[5]=f2bf(b.y); o[6]=f2bf(b.z); o[7]=f2bf(b.w);
  *(u16x8*)(d + i) = o;
}

// all four weight converts in one launch; range boundaries are multiples of
// 2048 elements so each block sees a uniform segment.
__global__ void k_cvt4(const float* __restrict__ s0, const float* __restrict__ s1,
                       const float* __restrict__ s2, const float* __restrict__ s3,
                       unsigned short* __restrict__ d0, unsigned short* __restrict__ d1,
                       unsigned short* __restrict__ d2, unsigned short* __restrict__ d3) {
  long i = (long)(blockIdx.x * 256 + threadIdx.x) * 8;
  const float* s; unsigned short* d;
  if (i < 1769472)             { s = s0;            d = d0; }
  else if (i < 2359296)        { s = s1 - 1769472;  d = d1 - 1769472; }
  else if (i < 21233664)       { s = s2 - 2359296;  d = d2 - 2359296; }
  else                         { s = s3 - 21233664; d = d3 - 21233664; }
  float4 a = *(const float4*)(s + i);
  float4 b = *(const float4*)(s + i + 4);
  u16x8 o;
  o[0]=f2bf(a.x); o[1]=f2bf(a.y); o[2]=f2bf(a.z); o[3]=f2bf(a.w);
  o[4]=f2bf(b.x); o[5]=f2bf(b.y); o[6]=f2bf(b.z); o[7]=f2bf(b.w);
  *(u16x8*)(d + i) = o;
}

// grid 576 (1D). XCD-swizzled: per XCD 4 row-tiles, col fastest in groups of 6.
__global__ __launch_bounds__(256, 2) void k_qkv(
    const unsigned short* __restrict__ hbf, const unsigned short* __restrict__ qkvw,
    unsigned short* __restrict__ qkvb)
{
  GEMM_PROLOGUE
  int f = blockIdx.x, xcd = f & 7, s = f >> 3;
  int cg = s / 24, rr = (s % 24) / 6, c = cg * 6 + s % 6;
  int row0 = (xcd * 4 + rr) * 128, col0 = c * 128;
  gemm_loop<true>(hbf, DIM_, qkvw, DIM_, 0, DIM_, row0, col0, lA, lB, acc);
#pragma unroll
  for (int mt = 0; mt < 4; ++mt)
#pragma unroll
    for (int nt = 0; nt < 4; ++nt)
#pragma unroll
      for (int i = 0; i < 4; ++i) {
        int m = row0 + wm + mt * 16 + g * 4 + i;
        int n = col0 + wn + nt * 16 + lm;
        int which = (n >= 1536) ? 2 : (n >= 768 ? 1 : 0);
        int d = n - which * 768;
        int head = d >> 6, hd = d & 63;
        int b = m >> 10, nn = m & 1023;
        int bh = b * 12 + head;
        size_t addr = (which < 2)
            ? ((size_t)which * 3145728u + (size_t)bh * 65536u + (size_t)nn * 64 + hd)
            : (6291456u + (size_t)bh * 65536u + (size_t)hd * 1024 + nn);  // V^T
        qkvb[addr] = f2bf(acc[mt][nt][i]);
      }
}

// grid 768 (1D). XCD-swizzled: per XCD 6 bh. Double-buffered K/V; lP is
// wave-private so no barrier between P-write and P-read (lgkmcnt dep only).
__global__ __launch_bounds__(256, 2) void k_attn(
    const unsigned short* __restrict__ qkv, unsigned short* __restrict__ abuf)
{
  __shared__ unsigned short lK[2][4096];
  __shared__ unsigned short lV[2][4096];     // V^T tile: [d][seq]
  __shared__ unsigned short lP[4][16 * 72];  // per-wave P, padded ld=72
  const int tid = threadIdx.x, lane = tid & 63, w = tid >> 6;
  const int g = lane >> 4, lm = lane & 15;
  const int f = blockIdx.x, xcd = f & 7, s = f >> 3;
  const int bh = xcd * 6 + (s >> 4);
  const int qt = s & 15;
  const unsigned short* qsec = qkv + (size_t)bh * 65536u;
  const unsigned short* ksec = qkv + 3145728u + (size_t)bh * 65536u;
  const unsigned short* vsec = qkv + 6291456u + (size_t)bh * 65536u;

  s16x8 bq[2];
  {
    const unsigned short* qp = qsec + (size_t)(qt * 64 + w * 16 + lm) * 64 + g * 8;
    bq[0] = *(const s16x8*)(qp);
    bq[1] = *(const s16x8*)(qp + 32);
  }
  f32x4 oacc[4];
#pragma unroll
  for (int dt = 0; dt < 4; ++dt) { oacc[dt][0]=0.f; oacc[dt][1]=0.f; oacc[dt][2]=0.f; oacc[dt][3]=0.f; }
  float m_i = -3.0e38f, l_i = 0.f;

  auto stage = [&](int kt, int p) {
#pragma unroll
    for (int it = 0; it < 2; ++it) {
      int c = (w * 2 + it) * 64 + lane;
      int r = c >> 3, sl = (c & 7) ^ (r & 7);
      async_cp16(ksec + (size_t)(kt * 64 + r) * 64 + sl * 8, lK[p] + (w * 2 + it) * 512);
      async_cp16(vsec + (size_t)r * 1024 + kt * 64 + sl * 8, lV[p] + (w * 2 + it) * 512);
    }
  };
  stage(0, 0);
  int p = 0;
  for (int kt = 0; kt < 16; ++kt) {
    __syncthreads();                       // KV buf p staged
    if (kt < 15) stage(kt + 1, p ^ 1);
    f32x4 st[4];
#pragma unroll
    for (int mt = 0; mt < 4; ++mt) {
      f32x4 z; z[0]=0.f; z[1]=0.f; z[2]=0.f; z[3]=0.f;
#pragma unroll
      for (int ks = 0; ks < 2; ++ks) {
        int ra = mt * 16 + lm;
        s16x8 a = *(const s16x8*)(lK[p] + ra * 64 + (((ks * 4 + g) ^ (ra & 7)) << 3));
        z = __builtin_amdgcn_mfma_f32_16x16x32_bf16(a, bq[ks], z, 0, 0, 0);
      }
      st[mt] = z;   // S^T[kcol = mt*16 + g*4 + i][qrow = lm]
    }
    float mx = -3.0e38f;
#pragma unroll
    for (int mt = 0; mt < 4; ++mt) {
      st[mt] *= 0.125f;
#pragma unroll
      for (int i = 0; i < 4; ++i) mx = fmaxf(mx, st[mt][i]);
    }
    mx = fmaxf(mx, __shfl_xor(mx, 16, 64));
    mx = fmaxf(mx, __shfl_xor(mx, 32, 64));
    float mnew = fmaxf(m_i, mx);
    float alpha = expf(m_i - mnew);
    float psum = 0.f;
#pragma unroll
    for (int mt = 0; mt < 4; ++mt) {
      u16x4 pk;
#pragma unroll
      for (int i = 0; i < 4; ++i) {
        float p2 = expf(st[mt][i] - mnew);
        psum += p2;
        pk[i] = f2bf(p2);
      }
      *(u16x4*)(&lP[w][lm * 72 + mt * 16 + g * 4]) = pk;
    }
    psum += __shfl_xor(psum, 16, 64);
    psum += __shfl_xor(psum, 32, 64);
    l_i = l_i * alpha + psum;
    m_i = mnew;
    float al[4];
#pragma unroll
    for (int i = 0; i < 4; ++i) al[i] = __shfl(alpha, (lane & 48) | (g * 4 + i), 64);
#pragma unroll
    for (int dt = 0; dt < 4; ++dt) {
#pragma unroll
      for (int i = 0; i < 4; ++i) oacc[dt][i] *= al[i];
    }
#pragma unroll
    for (int ks = 0; ks < 2; ++ks) {
      s16x8 ap = *(const s16x8*)(&lP[w][lm * 72 + ks * 32 + g * 8]);
#pragma unroll
      for (int dt = 0; dt < 4; ++dt) {
        int rv = dt * 16 + lm;
        s16x8 bv = *(const s16x8*)(lV[p] + rv * 64 + (((ks * 4 + g) ^ (rv & 7)) << 3));
        oacc[dt] = __builtin_amdgcn_mfma_f32_16x16x32_bf16(ap, bv, oacc[dt], 0, 0, 0);
      }
    }
    p ^= 1;
  }
  float linv[4];
#pragma unroll
  for (int i = 0; i < 4; ++i)
    linv[i] = 1.f / __shfl(l_i, (lane & 48) | (g * 4 + i), 64);
  int b = bh / 12, head = bh % 12;
#pragma unroll
  for (int dt = 0; dt < 4; ++dt)
#pragma unroll
    for (int i = 0; i < 4; ++i) {
      int q = qt * 64 + w * 16 + g * 4 + i;
      int col = head * 64 + dt * 16 + lm;
      abuf[(size_t)(b * 1024 + q) * DIM_ + col] = f2bf(oacc[dt][i] * linv[i]);
    }
}

__global__ __launch_bounds__(256, 2) void k_proj(
    const unsigned short* __restrict__ abuf, const unsigned short* __restrict__ projw,
    const float* __restrict__ projb, const float* __restrict__ x,
    float* __restrict__ x1)
{
  GEMM_PROLOGUE
  int row0 = blockIdx.x * 128, col0 = blockIdx.y * 128;
  gemm_loop<true>(abuf, DIM_, projw, DIM_, 0, DIM_, row0, col0, lA, lB, acc);
#pragma unroll
  for (int mt = 0; mt < 4; ++mt)
#pragma unroll
    for (int nt = 0; nt < 4; ++nt)
#pragma unroll
      for (int i = 0; i < 4; ++i) {
        int m = row0 + wm + mt * 16 + g * 4 + i;
        int n = col0 + wn + nt * 16 + lm;
        size_t idx = (size_t)m * DIM_ + n;
        x1[idx] = acc[mt][nt][i] + projb[n] + x[idx];
      }
}

// grid 1728 (1D). Per XCD 9 row-tiles, cols fastest in groups of 8.
template<bool BBF>
__global__ __launch_bounds__(256, 2) void k_ffn1(
    const unsigned short* __restrict__ xg, const void* __restrict__ w1,
    const float* __restrict__ b1, const int* __restrict__ off,
    unsigned short* __restrict__ hidden)
{
  int f = blockIdx.x, xcd = f & 7, s = f >> 3;
  int cg = s / 72, rr = (s % 72) >> 3, c = cg * 8 + (s & 7);
  int row0 = (xcd * 9 + rr) * 128, col0 = c * 128;
  if (row0 >= off[8]) return;
  int e = 0;
  while (!(row0 >= off[e] && row0 < off[e + 1])) ++e;
  GEMM_PROLOGUE
  const char* Bp = (const char*)w1 + (size_t)e * HID_ * DIM_ * (BBF ? 2 : 4);
  gemm_loop<BBF>(xg, DIM_, Bp, DIM_, 0, DIM_, row0, col0, lA, lB, acc);
#pragma unroll
  for (int mt = 0; mt < 4; ++mt)
#pragma unroll
    for (int nt = 0; nt < 4; ++nt)
#pragma unroll
      for (int i = 0; i < 4; ++i) {
        int m = row0 + wm + mt * 16 + g * 4 + i;
        int n = col0 + wn + nt * 16 + lm;
        float v = acc[mt][nt][i] + b1[e * HID_ + n];
        float ge = 0.5f * v * (1.f + erff(v * 0.70710678118654752f));
        hidden[(size_t)m * HID_ + n] = f2bf(ge);
      }
}

// grid 864 (1D): 72 row x 6 col x 2 K-halves (split-K). Partials in bf16.
template<bool BBF>
__global__ __launch_bounds__(256, 2) void k_ffn2(
    const unsigned short* __restrict__ hidden, const void* __restrict__ w2,
    const float* __restrict__ b2, const int* __restrict__ off,
    unsigned short* __restrict__ ye0, unsigned short* __restrict__ ye1)
{
  int f = blockIdx.x, xcd = f & 7, s = f >> 3;
  int cg = s / 54, rem = s % 54;
  int rr = rem / 6, kk = (rem % 6) / 3, c = cg * 3 + rem % 3;
  int row0 = (xcd * 9 + rr) * 128, col0 = c * 128;
  if (row0 >= off[8]) return;
  int e = 0;
  while (!(row0 >= off[e] && row0 < off[e + 1])) ++e;
  GEMM_PROLOGUE
  const char* Bp = (const char*)w2 + (size_t)e * DIM_ * HID_ * (BBF ? 2 : 4);
  gemm_loop<BBF>(hidden, HID_, Bp, HID_, kk * 1536, kk * 1536 + 1536, row0, col0, lA, lB, acc);
  unsigned short* yh = kk ? ye1 : ye0;
#pragma unroll
  for (int mt = 0; mt < 4; ++mt)
#pragma unroll
    for (int nt = 0; nt < 4; ++nt)
#pragma unroll
      for (int i = 0; i < 4; ++i) {
        int m = row0 + wm + mt * 16 + g * 4 + i;
        int n = col0 + wn + nt * 16 + lm;
        float v = acc[mt][nt][i] + (kk ? 0.f : b2[e * DIM_ + n]);
        yh[(size_t)m * DIM_ + n] = f2bf(v);
      }
}

__global__ __launch_bounds__(256) void k_ln1(
    const float* __restrict__ x, const float* __restrict__ gg,
    const float* __restrict__ bb, unsigned short* __restrict__ out)
{
  int t = blockIdx.x, tid = threadIdx.x;
  const float* xr = x + (size_t)t * DIM_;
  float v0 = xr[tid], v1 = xr[tid + 256], v2 = xr[tid + 512];
  float s = v0 + v1 + v2, q = v0 * v0 + v1 * v1 + v2 * v2;
  for (int o = 32; o; o >>= 1) { s += __shfl_xor(s, o, 64); q += __shfl_xor(q, o, 64); }
  __shared__ float red[8];
  int lane = tid & 63, w = tid >> 6;
  if (!lane) { red[w] = s; red[4 + w] = q; }
  __syncthreads();
  s = red[0] + red[1] + red[2] + red[3];
  q = red[4] + red[5] + red[6] + red[7];
  float mean = s * (1.f / 768.f);
  float rstd = rsqrtf(q * (1.f / 768.f) - mean * mean + 1e-5f);
  unsigned short* orow = out + (size_t)t * DIM_;
  orow[tid]       = f2bf((v0 - mean) * rstd * gg[tid]       + bb[tid]);
  orow[tid + 256] = f2bf((v1 - mean) * rstd * gg[tid + 256] + bb[tid + 256]);
  orow[tid + 512] = f2bf((v2 - mean) * rstd * gg[tid + 512] + bb[tid + 512]);
}

__global__ __launch_bounds__(256) void k_ln2gate(
    const float* __restrict__ x1, const float* __restrict__ gg,
    const float* __restrict__ bb, const float* __restrict__ gw,
    const float* __restrict__ gb, unsigned short* __restrict__ h2,
    int* __restrict__ topidx, float* __restrict__ tops)
{
  int t = blockIdx.x, tid = threadIdx.x;
  const float* xr = x1 + (size_t)t * DIM_;
  float v0 = xr[tid], v1 = xr[tid + 256], v2 = xr[tid + 512];
  float s = v0 + v1 + v2, q = v0 * v0 + v1 * v1 + v2 * v2;
  for (int o = 32; o; o >>= 1) { s += __shfl_xor(s, o, 64); q += __shfl_xor(q, o, 64); }
  __shared__ float red[8];
  __shared__ float part[32];
  int lane = tid & 63, w = tid >> 6;
  if (!lane) { red[w] = s; red[4 + w] = q; }
  __syncthreads();
  s = red[0] + red[1] + red[2] + red[3];
  q = red[4] + red[5] + red[6] + red[7];
  float mean = s * (1.f / 768.f);
  float rstd = rsqrtf(q * (1.f / 768.f) - mean * mean + 1e-5f);
  float y0 = (v0 - mean) * rstd * gg[tid]       + bb[tid];
  float y1 = (v1 - mean) * rstd * gg[tid + 256] + bb[tid + 256];
  float y2 = (v2 - mean) * rstd * gg[tid + 512] + bb[tid + 512];
  unsigned short* hrow = h2 + (size_t)t * DIM_;
  hrow[tid] = f2bf(y0); hrow[tid + 256] = f2bf(y1); hrow[tid + 512] = f2bf(y2);
#pragma unroll
  for (int e = 0; e < 8; ++e) {
    float p = y0 * gw[e * DIM_ + tid] + y1 * gw[e * DIM_ + tid + 256] + y2 * gw[e * DIM_ + tid + 512];
    for (int o = 32; o; o >>= 1) p += __shfl_xor(p, o, 64);
    if (!lane) part[e * 4 + w] = p;
  }
  __syncthreads();
  if (tid == 0) {
    float lg[8];
#pragma unroll
    for (int e = 0; e < 8; ++e)
      lg[e] = part[e * 4] + part[e * 4 + 1] + part[e * 4 + 2] + part[e * 4 + 3] + gb[e];
    int i0 = 0; float b0 = lg[0];
#pragma unroll
    for (int e = 1; e < 8; ++e) if (lg[e] > b0) { b0 = lg[e]; i0 = e; }
    int i1 = (i0 == 0) ? 1 : 0; float b1v = lg[i1];
#pragma unroll
    for (int e = 0; e < 8; ++e)
      if (e != i0 && lg[e] > b1v) { b1v = lg[e]; i1 = e; }
    float e1 = expf(b1v - b0);
    float s0 = 1.f / (1.f + e1);
    topidx[t * 2] = i0; topidx[t * 2 + 1] = i1;
    tops[t * 2] = s0;  tops[t * 2 + 1] = e1 / (1.f + e1);
  }
}

// single block: count (LDS atomics) -> padded offsets -> scatter positions
__global__ __launch_bounds__(1024) void k_route(
    const int* __restrict__ topidx, int* __restrict__ pos_of, int* __restrict__ off)
{
  __shared__ int scnt[8], soff[9], sfill[8];
  int tid = threadIdx.x;
  if (tid < 8) { scnt[tid] = 0; sfill[tid] = 0; }
  __syncthreads();
#pragma unroll
  for (int j = 0; j < 8; ++j)
    atomicAdd(&scnt[topidx[tid + j * 1024]], 1);
  __syncthreads();
  if (tid == 0) {
    int a = 0;
    for (int e = 0; e < 8; ++e) { soff[e] = a; off[e] = a; a += (scnt[e] + 127) & ~127; }
    soff[8] = a; off[8] = a;
  }
  __syncthreads();
#pragma unroll
  for (int j = 0; j < 8; ++j) {
    int i = tid + j * 1024;
    int e = topidx[i];
    pos_of[i] = soff[e] + atomicAdd(&sfill[e], 1);
  }
}

__global__ void k_gather(const unsigned short* __restrict__ h2,
                         const int* __restrict__ pos_of,
                         unsigned short* __restrict__ xg) {
  int pair = blockIdx.x, tid = threadIdx.x;   // 192 threads
  int pos = pos_of[pair], t = pair >> 1;
  ((uint2*)xg)[(size_t)pos * 192 + tid] = ((const uint2*)h2)[(size_t)t * 192 + tid];
}

__global__ void k_combine(const float* __restrict__ x1,
                          const unsigned short* __restrict__ y0h,
                          const unsigned short* __restrict__ y1h,
                          const int* __restrict__ pos_of, const float* __restrict__ tops,
                          float* __restrict__ out) {
  int t = blockIdx.x, tid = threadIdx.x;
  int p0 = pos_of[t * 2], p1 = pos_of[t * 2 + 1];
  float s0 = tops[t * 2], s1 = tops[t * 2 + 1];
  const float* xr = x1 + (size_t)t * DIM_;
  const unsigned short* a0 = y0h + (size_t)p0 * DIM_;
  const unsigned short* a1 = y1h + (size_t)p0 * DIM_;
  const unsigned short* b0 = y0h + (size_t)p1 * DIM_;
  const unsigned short* b1 = y1h + (size_t)p1 * DIM_;
  float* orow = out + (size_t)t * DIM_;
#pragma unroll
  for (int j = 0; j < 3; ++j) {
    int col = tid + j * 256;
    float ya = bf2f(a0[col]) + bf2f(a1[col]);
    float yb = bf2f(b0[col]) + bf2f(b1[col]);
    orow[col] = xr[col] + s0 * ya + s1 * yb;
  }
}

extern "C" void kernel_launch(void* const* d_in, const int* in_sizes, int n_in,
                              void* d_out, int out_size, void* d_ws, size_t ws_size,
                              hipStream_t stream) {
  const float* x     = (const float*)d_in[0];
  const float* ln1g  = (const float*)d_in[1];
  const float* ln1b  = (const float*)d_in[2];
  const float* qkvw  = (const float*)d_in[3];
  const float* projw = (const float*)d_in[4];
  const float* projb = (const float*)d_in[5];
  const float* ln2g  = (const float*)d_in[6];
  const float* ln2b  = (const float*)d_in[7];
  const float* gw    = (const float*)d_in[8];
  const float* gb    = (const float*)d_in[9];
  const float* w1    = (const float*)d_in[10];
  const float* b1    = (const float*)d_in[11];
  const float* w2    = (const float*)d_in[12];
  const float* b2    = (const float*)d_in[13];
  float* out = (float*)d_out;

  char* base = (char*)d_ws;
  unsigned short* hbf    = (unsigned short*)(base + 0);          // 6.29MB (reused as h2)
  unsigned short* qkvb   = (unsigned short*)(base + 6291456);    // 18.9MB (reused as xg)
  unsigned short* abuf   = (unsigned short*)(base + 25165824);   // 6.29MB
  float*          x1     = (float*)(base + 31457280);            // 12.6MB
  unsigned short* hidden = (unsigned short*)(base + 44040192);   // 56.6MB
  unsigned short* ye0    = (unsigned short*)(base + 100663296);  // 14.2MB bf16
  unsigned short* ye1    = (unsigned short*)(base + 114819072);  // 14.2MB bf16

  const size_t FULL_NEED = 209289320;   // + bf16 weight copies
  const bool full = ws_size >= FULL_NEED;
  unsigned short *wqkvbf, *wprojbf, *w1bf = nullptr, *w2bf = nullptr;
  char* small;
  if (full) {
    wqkvbf  = (unsigned short*)(base + 128974848);
    wprojbf = (unsigned short*)(base + 132513792);
    w1bf    = (unsigned short*)(base + 133693440);
    w2bf    = (unsigned short*)(base + 171442176);
    small   = base + 209190912;
  } else {
    wqkvbf  = (unsigned short*)(base + 44040192);
    wprojbf = (unsigned short*)(base + 44040192 + 3538944);
    small   = base + 128974848;
  }
  int*   topidx = (int*)small;
  float* tops   = (float*)(small + 32768);
  int*   pos_of = (int*)(small + 65536);
  int*   off    = (int*)(small + 98304);
  unsigned short* xg = qkvb;
  unsigned short* h2 = hbf;

  if (full) {
    k_cvt4<<<19584, 256, 0, stream>>>(qkvw, projw, w1, w2, wqkvbf, wprojbf, w1bf, w2bf);
  } else {
    k_cvt<<<864, 256, 0, stream>>>(qkvw, wqkvbf, 3 * DIM_ * DIM_);
    k_cvt<<<288, 256, 0, stream>>>(projw, wprojbf, DIM_ * DIM_);
  }
  k_ln1<<<NTOK, 256, 0, stream>>>(x, ln1g, ln1b, hbf);
  k_qkv<<<576, 256, 0, stream>>>(hbf, wqkvbf, qkvb);
  k_attn<<<768, 256, 0, stream>>>(qkvb, abuf);
  k_proj<<<dim3(32, 6), 256, 0, stream>>>(abuf, wprojbf, projb, x, x1);
  k_ln2gate<<<NTOK, 256, 0, stream>>>(x1, ln2g, ln2b, gw, gb, h2, topidx, tops);
  hipMemsetAsync(xg, 0, (size_t)CAP * DIM_ * 2, stream);
  k_route<<<1, 1024, 0, stream>>>(topidx, pos_of, off);
  k_gather<<<8192, 192, 0, stream>>>(h2, pos_of, xg);
  if (full) {
    k_ffn1<true><<<1728, 256, 0, stream>>>(xg, w1bf, b1, off, hidden);
    k_ffn2<true><<<864, 256, 0, stream>>>(hidden, w2bf, b2, off, ye0, ye1);
  } else {
    k_ffn1<false><<<1728, 256, 0, stream>>>(xg, w1, b1, off, hidden);
    k_ffn2<false><<<864, 256, 0, stream>>>(hidden, w2, b2, off, ye0, ye1);
  }
  k_combine<<<NTOK, 256, 0, stream>>>(x1, ye0, ye1, pos_of, tops, out);
}